// Round 7
// baseline (5419.613 us; speedup 1.0000x reference)
//
#include <hip/hip_runtime.h>
#include <hip/hip_bf16.h>

#define Bv 1024
#define Nv 64
#define Ev 1024
#define Dv 128
#define Hv 4
#define Lv 2
#define Kv 5
#define PAD 130   // bf16 LDS row stride

typedef __hip_bfloat16 bf16;

__device__ __forceinline__ float b2f(bf16 v) { return __bfloat162float(v); }
__device__ __forceinline__ bf16  f2b(float v) { return __float2bfloat16(v); }

// One block per batch element. Outputs are FLOAT32 (proven by R6 probe).
__global__ __launch_bounds__(256)
void gat_all(const int* __restrict__ x, const int* __restrict__ edge_index,
             const float* __restrict__ edge_attr, const float* __restrict__ attr_emb,
             const float* __restrict__ opt_emb, const float* __restrict__ prior,
             const float* __restrict__ Wl, const float* __restrict__ bl,
             const float* __restrict__ Wr, const float* __restrict__ br,
             const float* __restrict__ We, const float* __restrict__ att,
             const float* __restrict__ conv_bias, const float* __restrict__ ln_g,
             const float* __restrict__ ln_b, const float* __restrict__ W1,
             const float* __restrict__ b1, const float* __restrict__ W2,
             const float* __restrict__ b2,
             float* __restrict__ out_fscale, float* __restrict__ out_rel,
             float* __restrict__ out_hatT)
{
    const int b = blockIdx.x, tid = threadIdx.x;

    __shared__ bf16  hs [Nv * PAD];    // running h
    __shared__ bf16  xls[Nv * PAD];    // xl (layer) / hidden (MLP)
    __shared__ bf16  xrs[Nv * PAD];    // xr (layer) / T0 (MLP)
    __shared__ bf16  alphas[Ev * Hv];  // per-edge per-head logits
    __shared__ int   dsts[Ev];
    __shared__ float red [Nv * Hv];
    __shared__ float red2[Nv * Hv];
    __shared__ float relbuf[Nv];

    // ---- stage dst[] ----
    for (int e = tid; e < Ev; e += 256) dsts[e] = edge_index[Ev + e];

    // ---- T0 -> hs ----
    for (int idx = tid; idx < Nv * Dv; idx += 256) {
        int n = idx >> 7, d = idx & 127;
        float t0 = (attr_emb[n * Dv + d] + opt_emb[(n * Kv + x[b * Nv + n]) * Dv + d])
                   * prior[n];
        hs[n * PAD + d] = f2b(t0);
    }
    __syncthreads();

    for (int l = 0; l < Lv; ++l) {
        // ---- xl = h@Wl+bl, xr = h@Wr+br : one output element per thread (grid-stride) ----
        for (int idx = tid; idx < Nv * Dv; idx += 256) {
            int n = idx >> 7, j = idx & 127;
            float aL = bl[l * Dv + j], aR = br[l * Dv + j];
            for (int k = 0; k < Dv; ++k) {
                float hv = b2f(hs[n * PAD + k]);
                aL += hv * Wl[l * Dv * Dv + k * Dv + j];
                aR += hv * Wr[l * Dv * Dv + k * Dv + j];
            }
            xls[n * PAD + j] = f2b(aL);
            xrs[n * PAD + j] = f2b(aR);
        }
        __syncthreads();

        // ---- per-edge per-head logits ----
        for (int idx = tid; idx < Ev * Hv; idx += 256) {
            int e = idx >> 2, h = idx & 3;
            int s = edge_index[e], t = dsts[e];
            float ea = edge_attr[e];
            float acc = 0.f;
            for (int c = 0; c < 32; ++c) {
                float z = b2f(xls[s * PAD + h * 32 + c]) + b2f(xrs[t * PAD + h * 32 + c])
                          + ea * We[l * Dv + h * 32 + c];
                z = z > 0.f ? z : 0.2f * z;
                acc += z * att[l * Dv + h * 32 + c];
            }
            alphas[e * Hv + h] = f2b(acc);
        }
        __syncthreads();

        // ---- per (dst t, head h): linear-scan softmax + gather + LN + ELU + residual ----
        {
            const int t = tid & 63, h = tid >> 6;
            float mx = -3e38f;
            for (int e = 0; e < Ev; ++e)
                if (dsts[e] == t) mx = fmaxf(mx, b2f(alphas[e * Hv + h]));
            float den = 0.f;
            for (int e = 0; e < Ev; ++e)
                if (dsts[e] == t) den += expf(b2f(alphas[e * Hv + h]) - mx);
            float inv = den > 0.f ? 1.f / den : 0.f;
            float acc[32];
            for (int c = 0; c < 32; ++c) acc[c] = 0.f;
            for (int e = 0; e < Ev; ++e)
                if (dsts[e] == t) {
                    float a = expf(b2f(alphas[e * Hv + h]) - mx) * inv;
                    int s = edge_index[e];
                    for (int c = 0; c < 32; ++c)
                        acc[c] += a * b2f(xls[s * PAD + h * 32 + c]);
                }
            float sum = 0.f, sumsq = 0.f;
            for (int c = 0; c < 32; ++c) {
                float g = acc[c] + conv_bias[l * Dv + h * 32 + c];
                acc[c] = g;
                sum += g; sumsq += g * g;
            }
            red [t * Hv + h] = sum;
            red2[t * Hv + h] = sumsq;
            __syncthreads();
            float mu = (red [t * Hv] + red [t * Hv + 1] + red [t * Hv + 2] + red [t * Hv + 3]) * (1.f / 128.f);
            float ms = (red2[t * Hv] + red2[t * Hv + 1] + red2[t * Hv + 2] + red2[t * Hv + 3]) * (1.f / 128.f);
            float rstd = rsqrtf(ms - mu * mu + 1e-5f);
            for (int c = 0; c < 32; ++c) {
                float g = (acc[c] - mu) * rstd * ln_g[l * Dv + h * 32 + c]
                          + ln_b[l * Dv + h * 32 + c];
                g = g > 0.f ? g : (expf(g) - 1.f);   // elu
                int hi = t * PAD + h * 32 + c;
                hs[hi] = f2b(b2f(hs[hi]) + g);       // residual
            }
        }
        __syncthreads();
    }

    // ---- hat_T output (f32); T0 -> xrs ----
    for (int idx = tid; idx < Nv * Dv; idx += 256) {
        int n = idx >> 7, d = idx & 127;
        float t0 = (attr_emb[n * Dv + d] + opt_emb[(n * Kv + x[b * Nv + n]) * Dv + d])
                   * prior[n];
        xrs[n * PAD + d] = f2b(t0);
        size_t rb = ((size_t)(b * Nv + n)) * (2 * Dv);
        out_hatT[rb + d]      = t0;
        out_hatT[rb + Dv + d] = b2f(hs[n * PAD + d]);
    }
    __syncthreads();

    // ---- hidden = relu([T0,h] @ W1 + b1) -> xls ----
    for (int idx = tid; idx < Nv * Dv; idx += 256) {
        int n = idx >> 7, j = idx & 127;
        float a = b1[j];
        for (int k = 0; k < Dv; ++k) {
            a += b2f(xrs[n * PAD + k]) * W1[k * Dv + j];
            a += b2f(hs [n * PAD + k]) * W1[(Dv + k) * Dv + j];
        }
        xls[n * PAD + j] = f2b(a > 0.f ? a : 0.f);
    }
    __syncthreads();

    // ---- rel = sigmoid(hidden @ W2 + b2) (f32 out) ----
    {
        const int t = tid & 63, h = tid >> 6;
        float s = 0.f;
        for (int c = 0; c < 32; ++c)
            s += b2f(xls[t * PAD + h * 32 + c]) * W2[h * 32 + c];
        red[t * Hv + h] = s;
        __syncthreads();
        if (h == 0) {
            float z = red[t * Hv] + red[t * Hv + 1] + red[t * Hv + 2] + red[t * Hv + 3]
                      + b2[0];
            float r = 1.f / (1.f + expf(-z));
            relbuf[t] = r;
            out_rel[b * Nv + t] = r;
        }
    }
    __syncthreads();

    // ---- f_scale (f32 out) ----
    if (tid < Dv) {
        float num = 0.f, den = 0.f;
        for (int n = 0; n < Nv; ++n) {
            float r = relbuf[n];
            num += b2f(hs[n * PAD + tid]) * r;
            den += r;
        }
        out_fscale[b * Dv + tid] = num / (den + 1e-8f);
    }
}

extern "C" void kernel_launch(void* const* d_in, const int* in_sizes, int n_in,
                              void* d_out, int out_size, void* d_ws, size_t ws_size,
                              hipStream_t stream)
{
    const int*   x          = (const int*)  d_in[0];
    const int*   edge_index = (const int*)  d_in[1];
    const float* edge_attr  = (const float*)d_in[2];
    const float* attr_emb   = (const float*)d_in[3];
    const float* opt_emb    = (const float*)d_in[4];
    const float* prior      = (const float*)d_in[5];
    const float* Wl         = (const float*)d_in[6];
    const float* bl         = (const float*)d_in[7];
    const float* Wr         = (const float*)d_in[8];
    const float* br         = (const float*)d_in[9];
    const float* We         = (const float*)d_in[10];
    const float* att        = (const float*)d_in[11];
    const float* conv_bias  = (const float*)d_in[12];
    const float* ln_g       = (const float*)d_in[13];
    const float* ln_b       = (const float*)d_in[14];
    const float* W1         = (const float*)d_in[15];
    const float* b1         = (const float*)d_in[16];
    const float* W2         = (const float*)d_in[17];
    const float* b2         = (const float*)d_in[18];

    float* out        = (float*)d_out;
    float* out_fscale = out;                                      // B*D
    float* out_rel    = out + (size_t)Bv * Dv;                    // B*N
    float* out_hatT   = out + (size_t)Bv * Dv + (size_t)Bv * Nv;  // B*N*2D

    gat_all<<<Bv, 256, 0, stream>>>(x, edge_index, edge_attr, attr_emb, opt_emb,
                                    prior, Wl, bl, Wr, br, We, att, conv_bias,
                                    ln_g, ln_b, W1, b1, W2, b2,
                                    out_fscale, out_rel, out_hatT);
}

// Round 8
// 830.821 us; speedup vs baseline: 6.5232x; 6.5232x over previous
//
#include <hip/hip_runtime.h>
#include <hip/hip_bf16.h>

#define Bv 1024
#define Nv 64
#define Ev 1024
#define Dv 128
#define Hv 4
#define Lv 2
#define Kv 5
#define PAD 130   // bf16 LDS row stride

typedef __hip_bfloat16 bf16;

__device__ __forceinline__ float b2f(bf16 v) { return __bfloat162float(v); }
__device__ __forceinline__ bf16  f2b(float v) { return __float2bfloat16(v); }

// unpack u32 = 2 packed bf16 -> 2 floats
__device__ __forceinline__ void unpack2(unsigned int u, float& lo, float& hi) {
    union { unsigned int u; float f; } a, b;
    a.u = u << 16;
    b.u = u & 0xffff0000u;
    lo = a.f; hi = b.f;
}

// ---------------- CSR build: bucket edges by dst ----------------
__global__ void build_csr(const int* __restrict__ edge_index,
                          int* __restrict__ off, int* __restrict__ eid)
{
    __shared__ int cnt[Nv];
    int tid = threadIdx.x;
    if (tid < Nv) cnt[tid] = 0;
    __syncthreads();
    for (int e = tid; e < Ev; e += blockDim.x)
        atomicAdd(&cnt[edge_index[Ev + e]], 1);
    __syncthreads();
    if (tid == 0) {
        int s = 0;
        for (int t = 0; t < Nv; ++t) { int c = cnt[t]; off[t] = s; cnt[t] = s; s += c; }
        off[Nv] = s;
    }
    __syncthreads();
    for (int e = tid; e < Ev; e += blockDim.x) {
        int d = edge_index[Ev + e];
        int pos = atomicAdd(&cnt[d], 1);
        eid[pos] = e;
    }
}

// ---------------- fused per-batch-element kernel ----------------
__global__ __launch_bounds__(256)
void gat_fused(const int* __restrict__ x, const int* __restrict__ edge_index,
               const float* __restrict__ edge_attr, const float* __restrict__ attr_emb,
               const float* __restrict__ opt_emb, const float* __restrict__ prior,
               const float* __restrict__ Wl, const float* __restrict__ bl,
               const float* __restrict__ Wr, const float* __restrict__ br,
               const float* __restrict__ We, const float* __restrict__ att,
               const float* __restrict__ conv_bias, const float* __restrict__ ln_g,
               const float* __restrict__ ln_b, const float* __restrict__ W1,
               const float* __restrict__ b1, const float* __restrict__ W2,
               const float* __restrict__ b2,
               const int* __restrict__ csr_off, const int* __restrict__ csr_eid,
               float* __restrict__ out_fscale, float* __restrict__ out_rel,
               float* __restrict__ out_hatT)
{
    const int b = blockIdx.x;
    const int tid = threadIdx.x;

    __shared__ bf16 hs [Nv * PAD];
    __shared__ bf16 xls[Nv * PAD];
    __shared__ bf16 xrs[Nv * PAD];
    __shared__ bf16 alphas[Ev * Hv];
    __shared__ float red [Nv * Hv];
    __shared__ float red2[Nv * Hv];
    __shared__ float wecol[Dv];
    __shared__ float attv [Dv];
    __shared__ float relbuf[Nv];

    // ---- T0 -> hs ----
    for (int idx = tid; idx < Nv * Dv; idx += 256) {
        int n = idx >> 7, d = idx & 127;
        float t0 = (attr_emb[n * Dv + d] + opt_emb[(n * Kv + x[b * Nv + n]) * Dv + d])
                   * prior[n];
        hs[n * PAD + d] = f2b(t0);
    }

    for (int l = 0; l < Lv; ++l) {
        if (tid < Dv) {
            wecol[tid] = We[l * Dv + tid];
            attv[tid]  = att[l * Dv + tid];
        }
        __syncthreads();

        // ---- GEMM: xl = h@Wl+bl, xr = h@Wr+br. thread tile 4 rows x 8 cols ----
        {
            const int tx = tid & 15, ty = tid >> 4;
            const int j0 = tx * 8, r0 = ty * 4;
            float accL[4][8], accR[4][8];
            for (int i = 0; i < 4; ++i)
                for (int j = 0; j < 8; ++j) { accL[i][j] = 0.f; accR[i][j] = 0.f; }
            const float* wlp = Wl + (size_t)l * Dv * Dv;
            const float* wrp = Wr + (size_t)l * Dv * Dv;
            for (int k = 0; k < Dv; k += 2) {
                float4 l0a = *(const float4*)(wlp + k * Dv + j0);
                float4 l0b = *(const float4*)(wlp + k * Dv + j0 + 4);
                float4 l1a = *(const float4*)(wlp + (k + 1) * Dv + j0);
                float4 l1b = *(const float4*)(wlp + (k + 1) * Dv + j0 + 4);
                float4 r0a = *(const float4*)(wrp + k * Dv + j0);
                float4 r0b = *(const float4*)(wrp + k * Dv + j0 + 4);
                float4 r1a = *(const float4*)(wrp + (k + 1) * Dv + j0);
                float4 r1b = *(const float4*)(wrp + (k + 1) * Dv + j0 + 4);
                float wl0[8] = {l0a.x, l0a.y, l0a.z, l0a.w, l0b.x, l0b.y, l0b.z, l0b.w};
                float wl1[8] = {l1a.x, l1a.y, l1a.z, l1a.w, l1b.x, l1b.y, l1b.z, l1b.w};
                float wr0[8] = {r0a.x, r0a.y, r0a.z, r0a.w, r0b.x, r0b.y, r0b.z, r0b.w};
                float wr1[8] = {r1a.x, r1a.y, r1a.z, r1a.w, r1b.x, r1b.y, r1b.z, r1b.w};
                for (int i = 0; i < 4; ++i) {
                    float h0, h1;
                    unpack2(*(const unsigned int*)&hs[(r0 + i) * PAD + k], h0, h1);
                    for (int j = 0; j < 8; ++j) {
                        accL[i][j] += h0 * wl0[j] + h1 * wl1[j];
                        accR[i][j] += h0 * wr0[j] + h1 * wr1[j];
                    }
                }
            }
            for (int i = 0; i < 4; ++i)
                for (int j = 0; j < 8; ++j) {
                    xls[(r0 + i) * PAD + j0 + j] = f2b(accL[i][j] + bl[l * Dv + j0 + j]);
                    xrs[(r0 + i) * PAD + j0 + j] = f2b(accR[i][j] + br[l * Dv + j0 + j]);
                }
        }
        __syncthreads();

        // ---- per-edge per-head logits (wave-parallel) ----
        {
            const int h = tid >> 6, lane = tid & 63;
            for (int it = 0; it < Ev / 64; ++it) {
                int e = it * 64 + lane;
                int s = edge_index[e], t = edge_index[Ev + e];
                float ea = edge_attr[e];
                float acc = 0.f;
                int bs = s * PAD + h * 32, bt = t * PAD + h * 32;
                for (int c = 0; c < 32; c += 2) {
                    float xl0, xl1, xr0, xr1;
                    unpack2(*(const unsigned int*)&xls[bs + c], xl0, xl1);
                    unpack2(*(const unsigned int*)&xrs[bt + c], xr0, xr1);
                    float z0 = xl0 + xr0 + ea * wecol[h * 32 + c];
                    float z1 = xl1 + xr1 + ea * wecol[h * 32 + c + 1];
                    z0 = z0 > 0.f ? z0 : 0.2f * z0;
                    z1 = z1 > 0.f ? z1 : 0.2f * z1;
                    acc += z0 * attv[h * 32 + c] + z1 * attv[h * 32 + c + 1];
                }
                alphas[e * Hv + h] = f2b(acc);
            }
        }
        __syncthreads();

        // ---- per (dst, head) via CSR: softmax + gather + LN + ELU + residual ----
        {
            const int t = tid & 63, h = tid >> 6;
            int beg = csr_off[t], end = csr_off[t + 1];
            float mx = -3e38f;
            for (int idx = beg; idx < end; ++idx)
                mx = fmaxf(mx, b2f(alphas[csr_eid[idx] * Hv + h]));
            float den = 0.f;
            for (int idx = beg; idx < end; ++idx) {
                int e = csr_eid[idx];
                float ex = expf(b2f(alphas[e * Hv + h]) - mx);
                den += ex;
                alphas[e * Hv + h] = f2b(ex);   // edge owned by exactly one (t,h)
            }
            float acc[32];
            for (int c = 0; c < 32; ++c) acc[c] = 0.f;
            float inv_den = (end > beg) ? 1.f / den : 0.f;
            for (int idx = beg; idx < end; ++idx) {
                int e = csr_eid[idx];
                int s = edge_index[e];
                float a = b2f(alphas[e * Hv + h]) * inv_den;
                int bs = s * PAD + h * 32;
                for (int c = 0; c < 32; c += 2) {
                    float m0, m1;
                    unpack2(*(const unsigned int*)&xls[bs + c], m0, m1);
                    acc[c] += a * m0; acc[c + 1] += a * m1;
                }
            }
            float sum = 0.f, sumsq = 0.f;
            for (int c = 0; c < 32; ++c) {
                float g = acc[c] + conv_bias[l * Dv + h * 32 + c];
                acc[c] = g;
                sum += g; sumsq += g * g;
            }
            red [t * Hv + h] = sum;
            red2[t * Hv + h] = sumsq;
            __syncthreads();
            float mu = (red [t * Hv] + red [t * Hv + 1] + red [t * Hv + 2] + red [t * Hv + 3]) * (1.f / 128.f);
            float ms = (red2[t * Hv] + red2[t * Hv + 1] + red2[t * Hv + 2] + red2[t * Hv + 3]) * (1.f / 128.f);
            float rstd = rsqrtf(ms - mu * mu + 1e-5f);
            for (int c = 0; c < 32; ++c) {
                float g = (acc[c] - mu) * rstd * ln_g[l * Dv + h * 32 + c]
                          + ln_b[l * Dv + h * 32 + c];
                g = g > 0.f ? g : (expf(g) - 1.f);   // elu
                int hi = t * PAD + h * 32 + c;
                hs[hi] = f2b(b2f(hs[hi]) + g);       // residual
            }
        }
        __syncthreads();
    }

    // ---- hat_T (f32 out); T0 -> xrs; preload W2 ----
    if (tid < Dv) wecol[tid] = W2[tid];
    for (int idx = tid; idx < Nv * Dv; idx += 256) {
        int n = idx >> 7, d = idx & 127;
        float t0 = (attr_emb[n * Dv + d] + opt_emb[(n * Kv + x[b * Nv + n]) * Dv + d])
                   * prior[n];
        xrs[n * PAD + d] = f2b(t0);
        size_t rb = ((size_t)(b * Nv + n)) * (2 * Dv);
        out_hatT[rb + d]      = t0;
        out_hatT[rb + Dv + d] = b2f(hs[n * PAD + d]);
    }
    __syncthreads();

    // ---- hidden = relu([T0,h] @ W1 + b1) -> xls ----
    {
        const int tx = tid & 15, ty = tid >> 4;
        const int j0 = tx * 8, r0 = ty * 4;
        float acc[4][8];
        for (int i = 0; i < 4; ++i)
            for (int j = 0; j < 8; ++j) acc[i][j] = 0.f;
        for (int half = 0; half < 2; ++half) {
            const bf16* src = half ? hs : xrs;
            const float* w1p = W1 + (size_t)half * Dv * Dv;
            for (int k = 0; k < Dv; k += 2) {
                float4 a0 = *(const float4*)(w1p + k * Dv + j0);
                float4 a1 = *(const float4*)(w1p + k * Dv + j0 + 4);
                float4 c0 = *(const float4*)(w1p + (k + 1) * Dv + j0);
                float4 c1 = *(const float4*)(w1p + (k + 1) * Dv + j0 + 4);
                float w0[8]  = {a0.x, a0.y, a0.z, a0.w, a1.x, a1.y, a1.z, a1.w};
                float w1v[8] = {c0.x, c0.y, c0.z, c0.w, c1.x, c1.y, c1.z, c1.w};
                for (int i = 0; i < 4; ++i) {
                    float h0, h1;
                    unpack2(*(const unsigned int*)&src[(r0 + i) * PAD + k], h0, h1);
                    for (int j = 0; j < 8; ++j)
                        acc[i][j] += h0 * w0[j] + h1 * w1v[j];
                }
            }
        }
        for (int i = 0; i < 4; ++i)
            for (int j = 0; j < 8; ++j) {
                float v = acc[i][j] + b1[j0 + j];
                xls[(r0 + i) * PAD + j0 + j] = f2b(v > 0.f ? v : 0.f);
            }
    }
    __syncthreads();

    // ---- rel = sigmoid(hidden @ W2 + b2) (f32 out) ----
    {
        const int t = tid & 63, h = tid >> 6;
        float s = 0.f;
        for (int c = 0; c < 32; c += 2) {
            float h0, h1;
            unpack2(*(const unsigned int*)&xls[t * PAD + h * 32 + c], h0, h1);
            s += h0 * wecol[h * 32 + c] + h1 * wecol[h * 32 + c + 1];
        }
        red[t * Hv + h] = s;
        __syncthreads();
        if (h == 0) {
            float z = red[t * Hv] + red[t * Hv + 1] + red[t * Hv + 2] + red[t * Hv + 3]
                      + b2[0];
            float r = 1.f / (1.f + expf(-z));
            relbuf[t] = r;
            out_rel[b * Nv + t] = r;
        }
    }
    __syncthreads();

    // ---- f_scale (f32 out) ----
    if (tid < Dv) {
        float num = 0.f, den = 0.f;
        for (int n = 0; n < Nv; ++n) {
            float r = relbuf[n];
            num += b2f(hs[n * PAD + tid]) * r;
            den += r;
        }
        out_fscale[b * Dv + tid] = num / (den + 1e-8f);
    }
}

extern "C" void kernel_launch(void* const* d_in, const int* in_sizes, int n_in,
                              void* d_out, int out_size, void* d_ws, size_t ws_size,
                              hipStream_t stream)
{
    const int*   x          = (const int*)  d_in[0];
    const int*   edge_index = (const int*)  d_in[1];
    const float* edge_attr  = (const float*)d_in[2];
    const float* attr_emb   = (const float*)d_in[3];
    const float* opt_emb    = (const float*)d_in[4];
    const float* prior      = (const float*)d_in[5];
    const float* Wl         = (const float*)d_in[6];
    const float* bl         = (const float*)d_in[7];
    const float* Wr         = (const float*)d_in[8];
    const float* br         = (const float*)d_in[9];
    const float* We         = (const float*)d_in[10];
    const float* att        = (const float*)d_in[11];
    const float* conv_bias  = (const float*)d_in[12];
    const float* ln_g       = (const float*)d_in[13];
    const float* ln_b       = (const float*)d_in[14];
    const float* W1         = (const float*)d_in[15];
    const float* b1         = (const float*)d_in[16];
    const float* W2         = (const float*)d_in[17];
    const float* b2         = (const float*)d_in[18];

    int* csr_off = (int*)d_ws;          // Nv+1 ints
    int* csr_eid = (int*)d_ws + 128;    // Ev ints

    float* out        = (float*)d_out;
    float* out_fscale = out;                                      // B*D
    float* out_rel    = out + (size_t)Bv * Dv;                    // B*N
    float* out_hatT   = out + (size_t)Bv * Dv + (size_t)Bv * Nv;  // B*N*2D

    build_csr<<<1, 256, 0, stream>>>(edge_index, csr_off, csr_eid);
    gat_fused<<<Bv, 256, 0, stream>>>(x, edge_index, edge_attr, attr_emb, opt_emb,
                                      prior, Wl, bl, Wr, br, We, att, conv_bias,
                                      ln_g, ln_b, W1, b1, W2, b2,
                                      csr_off, csr_eid,
                                      out_fscale, out_rel, out_hatT);
}